// Round 2
// baseline (701.860 us; speedup 1.0000x reference)
//
#include <hip/hip_runtime.h>
#include <hip/hip_bf16.h>

// Problem constants
#define BB 16
#define CC 256
#define HH 32
#define WW 32
#define HWP 1024          // H*W
#define DH 32
#define HEADS 8
#define WSZ 4
#define KTOP 4
#define MRC 1024          // MR*C
#define C3 768            // 3*C
#define NWIN 64
#define WS 16
#define EPSV 1e-5f

__device__ __forceinline__ float gelu_f(float x) {
    // exact GELU: x * 0.5 * (1 + erf(x/sqrt(2)))
    return 0.5f * x * (1.0f + erff(x * 0.70710678118654752f));
}

// ---------------------------------------------------------------- K1: bn0+gelu
__global__ __launch_bounds__(256) void bn0_gelu_k(const float* __restrict__ x,
    const float* __restrict__ g, const float* __restrict__ bta,
    const float* __restrict__ mu, const float* __restrict__ var,
    float* __restrict__ out) {
    int i = blockIdx.x * 256 + threadIdx.x;     // 16*256*1024 total
    int c = (i >> 10) & 255;
    float s = g[c] * rsqrtf(var[c] + EPSV);
    float y = (x[i] - mu[c]) * s + bta[c];
    out[i] = gelu_f(y);
}

// ---------------------------------------------------------------- K2: GEMM + fused epilogues
// C[b][m][n] = sum_k A[m][k] * X[b][k][n],  N = 1024 fixed.
// MODE 0: plain store (qkv)
// MODE 1: out = res + C + bias  (merge; res = original x, bias = b_merge)
// MODE 2: out = gelu(bn1(C))
// MODE 3: out = bn3(C) + res   (res = xr) -> float (final output)
template <int MODE>
__global__ __launch_bounds__(256) void gemm_ep(
    const float* __restrict__ A, const float* __restrict__ X,
    float* __restrict__ Out,
    const float* __restrict__ res,
    const float* __restrict__ p0, const float* __restrict__ p1,
    const float* __restrict__ p2, const float* __restrict__ p3,
    int M, int Kd) {
    __shared__ float As[16][64];
    __shared__ float Bs[16][64];
    float acc[4][4] = {{0.f}};
    const int t = threadIdx.x;
    const int tn = t & 15, tm = t >> 4;
    const int n0 = blockIdx.x * 64;
    const int m0 = blockIdx.y * 64;
    const int b  = blockIdx.z;
    const float* Xb = X + (size_t)b * Kd * HWP;

    for (int k0 = 0; k0 < Kd; k0 += 16) {
        // A tile: 64 rows x 16 cols, one float4 per thread, store transposed
        {
            int m  = t >> 2;
            int k4 = (t & 3) << 2;
            float4 a4 = *(const float4*)(A + (size_t)(m0 + m) * Kd + k0 + k4);
            As[k4 + 0][m] = a4.x; As[k4 + 1][m] = a4.y;
            As[k4 + 2][m] = a4.z; As[k4 + 3][m] = a4.w;
            // B tile: 16 rows x 64 cols, one float4 per thread
            int r  = t >> 4;
            int c4 = (t & 15) << 2;
            *(float4*)&Bs[r][c4] = *(const float4*)(Xb + (size_t)(k0 + r) * HWP + n0 + c4);
        }
        __syncthreads();
        #pragma unroll
        for (int kk = 0; kk < 16; ++kk) {
            float4 av = *(const float4*)&As[kk][tm << 2];
            float4 bv = *(const float4*)&Bs[kk][tn << 2];
            float a0[4] = {av.x, av.y, av.z, av.w};
            float b0[4] = {bv.x, bv.y, bv.z, bv.w};
            #pragma unroll
            for (int i = 0; i < 4; ++i)
                #pragma unroll
                for (int j = 0; j < 4; ++j)
                    acc[i][j] += a0[i] * b0[j];
        }
        __syncthreads();
    }

    #pragma unroll
    for (int i = 0; i < 4; ++i) {
        int m = m0 + (tm << 2) + i;
        float sc = 0.f, mean = 0.f, beta = 0.f, bias = 0.f;
        if (MODE == 2 || MODE == 3) {
            sc = p0[m] * rsqrtf(p3[m] + EPSV);
            mean = p2[m]; beta = p1[m];
        }
        if (MODE == 1) bias = p0[m];
        #pragma unroll
        for (int j = 0; j < 4; ++j) {
            int n = n0 + (tn << 2) + j;
            size_t oidx = ((size_t)b * M + m) * HWP + n;
            float v = acc[i][j];
            if (MODE == 0) {
                Out[oidx] = v;
            } else if (MODE == 1) {
                Out[oidx] = res[oidx] + v + bias;
            } else if (MODE == 2) {
                Out[oidx] = gelu_f((v - mean) * sc + beta);
            } else {
                Out[oidx] = (v - mean) * sc + beta + res[oidx];
            }
        }
    }
}

// ---------------------------------------------------------------- K3: window means + affinity + top-4
__global__ __launch_bounds__(256) void topk_k(const float* __restrict__ qkv,
                                              int* __restrict__ idx_out) {
    int bh = blockIdx.x;            // b*8 + h
    int b = bh >> 3, h = bh & 7;
    __shared__ float qm[64][32];
    __shared__ float km[64][32];
    __shared__ float wsc[64][64];
    const float* qbase = qkv + ((size_t)b * C3 + h * DH) * HWP;
    const float* kbase = qkv + ((size_t)b * C3 + CC + h * DH) * HWP;
    int t = threadIdx.x;
    for (int e = t; e < 2048; e += 256) {
        int win = e >> 5, d = e & 31;
        int base = (win >> 3) * 128 + (win & 7) * 4;   // (wy*4)*32 + wx*4
        float sq = 0.f, sk = 0.f;
        #pragma unroll
        for (int ty = 0; ty < 4; ++ty)
            #pragma unroll
            for (int tx = 0; tx < 4; ++tx) {
                int hw = base + ty * 32 + tx;
                sq += qbase[(size_t)d * HWP + hw];
                sk += kbase[(size_t)d * HWP + hw];
            }
        qm[win][d] = sq * (1.f / 16.f);
        km[win][d] = sk * (1.f / 16.f);
    }
    __syncthreads();
    for (int e = t; e < 4096; e += 256) {
        int i = e >> 6, j = e & 63;
        float s = 0.f;
        #pragma unroll
        for (int d = 0; d < 32; ++d) s += qm[i][d] * km[j][d];
        wsc[i][j] = s;   // positive scale doesn't change ranking
    }
    __syncthreads();
    if (t < 64) {
        float bv[4] = {-1e30f, -1e30f, -1e30f, -1e30f};
        int   bi[4] = {0, 0, 0, 0};
        for (int j = 0; j < 64; ++j) {
            float v = wsc[t][j];
            if (v > bv[3]) {
                int p = 3;
                while (p > 0 && v > bv[p - 1]) {
                    bv[p] = bv[p - 1]; bi[p] = bi[p - 1]; --p;
                }
                bv[p] = v; bi[p] = j;
            }
        }
        int* o = idx_out + (bh * 64 + t) * 4;
        o[0] = bi[0]; o[1] = bi[1]; o[2] = bi[2]; o[3] = bi[3];
    }
}

// ---------------------------------------------------------------- K4: gathered window attention + unwin
__global__ __launch_bounds__(256) void attn_k(const float* __restrict__ qkv,
                                              const int* __restrict__ idx,
                                              float* __restrict__ msg) {
    int blk = blockIdx.x;           // (b*8+h)*64 + win
    int win = blk & 63;
    int bh = blk >> 6;
    int b = bh >> 3, h = bh & 7;
    __shared__ float qs[16][32];
    __shared__ float ks[64][32];
    __shared__ float vs[64][32];
    __shared__ float sc[16][64];
    __shared__ int widx[4];
    int t = threadIdx.x;
    if (t < 4) widx[t] = idx[(bh * 64 + win) * 4 + t];
    __syncthreads();
    const float* qbase = qkv + ((size_t)b * C3 + h * DH) * HWP;
    const float* kbase = qkv + ((size_t)b * C3 + CC + h * DH) * HWP;
    const float* vbase = qkv + ((size_t)b * C3 + 2 * CC + h * DH) * HWP;
    int qb = (win >> 3) * 128 + (win & 7) * 4;
    for (int e = t; e < 512; e += 256) {
        int tok = e >> 5, d = e & 31;
        int hw = qb + (tok >> 2) * 32 + (tok & 3);
        qs[tok][d] = qbase[(size_t)d * HWP + hw];
    }
    for (int e = t; e < 2048; e += 256) {
        int key = e >> 5, d = e & 31;
        int wsel = widx[key >> 4];
        int tok = key & 15;
        int hw = (wsel >> 3) * 128 + (wsel & 7) * 4 + (tok >> 2) * 32 + (tok & 3);
        ks[key][d] = kbase[(size_t)d * HWP + hw];
        vs[key][d] = vbase[(size_t)d * HWP + hw];
    }
    __syncthreads();
    const float scale = 0.17677669529663688f;   // 1/sqrt(32)
    for (int e = t; e < 1024; e += 256) {
        int r = e >> 6, cidx = e & 63;
        float s = 0.f;
        #pragma unroll
        for (int d = 0; d < 32; ++d) s += qs[r][d] * ks[cidx][d];
        sc[r][cidx] = s * scale;
    }
    __syncthreads();
    {   // softmax over 64: 16 rows x 16 lanes, 4 cols each
        int r = t >> 4, c0 = (t & 15) << 2;
        float v0 = sc[r][c0], v1 = sc[r][c0 + 1], v2 = sc[r][c0 + 2], v3 = sc[r][c0 + 3];
        float mx = fmaxf(fmaxf(v0, v1), fmaxf(v2, v3));
        #pragma unroll
        for (int m = 1; m < 16; m <<= 1) mx = fmaxf(mx, __shfl_xor(mx, m));
        float e0 = expf(v0 - mx), e1 = expf(v1 - mx), e2 = expf(v2 - mx), e3 = expf(v3 - mx);
        float sm = e0 + e1 + e2 + e3;
        #pragma unroll
        for (int m = 1; m < 16; m <<= 1) sm += __shfl_xor(sm, m);
        float inv = 1.0f / sm;
        sc[r][c0] = e0 * inv; sc[r][c0 + 1] = e1 * inv;
        sc[r][c0 + 2] = e2 * inv; sc[r][c0 + 3] = e3 * inv;
    }
    __syncthreads();
    for (int e = t; e < 512; e += 256) {
        int tok = e >> 5, d = e & 31;
        float s = 0.f;
        #pragma unroll
        for (int kk = 0; kk < 64; ++kk) s += sc[tok][kk] * vs[kk][d];
        int hw = qb + (tok >> 2) * 32 + (tok & 3);
        msg[((size_t)b * CC + h * DH + d) * HWP + hw] = s;   // unwin fused
    }
}

// ---------------------------------------------------------------- K5: depthwise 3x3 + bn2 + gelu
__global__ __launch_bounds__(256) void dw_bn_gelu_k(const float* __restrict__ h1,
    const float* __restrict__ wdw,
    const float* __restrict__ g, const float* __restrict__ bta,
    const float* __restrict__ mu, const float* __restrict__ var,
    float* __restrict__ out) {
    int i = blockIdx.x * 256 + threadIdx.x;     // 16*1024*1024 total
    int xw = i & 31, yh = (i >> 5) & 31, ch = (i >> 10) & 1023;
    const float* plane = h1 + (size_t)(i >> 10) * HWP;
    const float* w9 = wdw + ch * 9;
    float acc = 0.f;
    #pragma unroll
    for (int dy = -1; dy <= 1; ++dy) {
        int yy = yh + dy;
        if (yy < 0 || yy > 31) continue;
        #pragma unroll
        for (int dx = -1; dx <= 1; ++dx) {
            int xx = xw + dx;
            if (xx < 0 || xx > 31) continue;
            acc += plane[yy * 32 + xx] * w9[(dy + 1) * 3 + (dx + 1)];
        }
    }
    float s = g[ch] * rsqrtf(var[ch] + EPSV);
    out[i] = gelu_f((acc - mu[ch]) * s + bta[ch]);
}

// ---------------------------------------------------------------- launch
extern "C" void kernel_launch(void* const* d_in, const int* in_sizes, int n_in,
                              void* d_out, int out_size, void* d_ws, size_t ws_size,
                              hipStream_t stream) {
    const float* x      = (const float*)d_in[0];
    const float* bn0_g  = (const float*)d_in[1];
    const float* bn0_b  = (const float*)d_in[2];
    const float* bn0_m  = (const float*)d_in[3];
    const float* bn0_v  = (const float*)d_in[4];
    const float* w_qkv  = (const float*)d_in[5];
    const float* w_merge= (const float*)d_in[6];
    const float* b_merge= (const float*)d_in[7];
    const float* w1     = (const float*)d_in[8];
    const float* bn1_g  = (const float*)d_in[9];
    const float* bn1_b  = (const float*)d_in[10];
    const float* bn1_m  = (const float*)d_in[11];
    const float* bn1_v  = (const float*)d_in[12];
    const float* dw     = (const float*)d_in[13];
    const float* bn2_g  = (const float*)d_in[14];
    const float* bn2_b  = (const float*)d_in[15];
    const float* bn2_m  = (const float*)d_in[16];
    const float* bn2_v  = (const float*)d_in[17];
    const float* w2     = (const float*)d_in[18];
    const float* bn3_g  = (const float*)d_in[19];
    const float* bn3_b  = (const float*)d_in[20];
    const float* bn3_m  = (const float*)d_in[21];
    const float* bn3_v  = (const float*)d_in[22];
    float* out = (float*)d_out;   // reference output dtype is float32

    // workspace layout (floats); total ~218.3 MB
    float* ws = (float*)d_ws;
    float* h0  = ws;                          // 4,194,304  (reused as msg)
    float* qkv = ws + 4194304;                // 12,582,912
    float* xr  = ws + 16777216;               // 4,194,304
    float* h1  = ws + 20971520;               // 16,777,216
    float* h2  = ws + 37748736;               // 16,777,216
    int*   idx = (int*)(ws + 54525952);       // 32,768 ints

    // 1. h0 = gelu(bn0(x))
    bn0_gelu_k<<<16384, 256, 0, stream>>>(x, bn0_g, bn0_b, bn0_m, bn0_v, h0);
    // 2. qkv = w_qkv @ h0
    gemm_ep<0><<<dim3(16, 12, 16), 256, 0, stream>>>(w_qkv, h0, qkv,
        nullptr, nullptr, nullptr, nullptr, nullptr, C3, CC);
    // 3. top-k window indices
    topk_k<<<128, 256, 0, stream>>>(qkv, idx);
    // 4. attention -> msg (reuse h0)
    attn_k<<<8192, 256, 0, stream>>>(qkv, idx, h0);
    // 5. xr = x + w_merge @ msg + b_merge
    gemm_ep<1><<<dim3(16, 4, 16), 256, 0, stream>>>(w_merge, h0, xr,
        x, b_merge, nullptr, nullptr, nullptr, CC, CC);
    // 6. h1 = gelu(bn1(w1 @ xr))
    gemm_ep<2><<<dim3(16, 16, 16), 256, 0, stream>>>(w1, xr, h1,
        nullptr, bn1_g, bn1_b, bn1_m, bn1_v, MRC, CC);
    // 7. h2 = gelu(bn2(dwconv3x3(h1)))
    dw_bn_gelu_k<<<65536, 256, 0, stream>>>(h1, dw, bn2_g, bn2_b, bn2_m, bn2_v, h2);
    // 8. out = bn3(w2 @ h2) + xr   (float32 output)
    gemm_ep<3><<<dim3(16, 4, 16), 256, 0, stream>>>(w2, h2, out,
        xr, bn3_g, bn3_b, bn3_m, bn3_v, CC, MRC);
}

// Round 4
// 495.520 us; speedup vs baseline: 1.4164x; 1.4164x over previous
//
#include <hip/hip_runtime.h>
#include <hip/hip_bf16.h>

#define EPSV 1e-5f

typedef short bf16x8 __attribute__((ext_vector_type(8)));
typedef float f32x4 __attribute__((ext_vector_type(4)));

__device__ __forceinline__ float gelu_f(float x) {
    return 0.5f * x * (1.0f + erff(x * 0.70710678118654752f));
}
__device__ __forceinline__ float b2f(unsigned short u) {
    union { float f; unsigned i; } c; c.i = ((unsigned)u) << 16; return c.f;
}
__device__ __forceinline__ unsigned short f2b(float f) {
    __hip_bfloat16 h = __float2bfloat16(f);
    return *reinterpret_cast<unsigned short*>(&h);
}
// async global->LDS, 16B per lane; LDS dest = wave-uniform base + lane*16
__device__ __forceinline__ void gload16(const unsigned short* g, unsigned short* l) {
    __builtin_amdgcn_global_load_lds(
        (const __attribute__((address_space(1))) void*)g,
        (__attribute__((address_space(3))) void*)l, 16, 0, 0);
}

// ---------------------------------------------------------------- weight f32->bf16
__global__ __launch_bounds__(256) void wcvt_k(const float* __restrict__ w,
                                              unsigned short* __restrict__ o, int n4) {
    int i = blockIdx.x * 256 + threadIdx.x;
    if (i >= n4) return;
    float4 v = ((const float4*)w)[i];
    ushort4 u = make_ushort4(f2b(v.x), f2b(v.y), f2b(v.z), f2b(v.w));
    ((ushort4*)o)[i] = u;
}

// ---------------------------------------------------------------- bn0+gelu + NCHW->NHWC
// writes x_t (raw x, f32 NHWC) and h0b (gelu(bn0(x)), bf16 NHWC)
__global__ __launch_bounds__(256) void bn0tr_k(const float* __restrict__ x,
    const float* __restrict__ g, const float* __restrict__ bt,
    const float* __restrict__ mu, const float* __restrict__ va,
    unsigned short* __restrict__ h0b, float* __restrict__ xt) {
    __shared__ float tile[64][65];
    int hw0 = blockIdx.x * 64, c0 = blockIdx.y * 64, b = blockIdx.z;
    int t = threadIdx.x;
    int cl = t >> 6, hl = t & 63;
    #pragma unroll
    for (int r = 0; r < 16; ++r)
        tile[r * 4 + cl][hl] = x[((size_t)(b * 256 + c0 + r * 4 + cl)) * 1024 + hw0 + hl];
    __syncthreads();
    int c = c0 + (t & 63);
    float s = g[c] * rsqrtf(va[c] + EPSV);
    float m_ = mu[c], be = bt[c];
    #pragma unroll
    for (int r = 0; r < 16; ++r) {
        int hl2 = r * 4 + (t >> 6);
        float v = tile[t & 63][hl2];
        size_t o = ((size_t)(b * 1024 + hw0 + hl2)) * 256 + c;
        xt[o] = v;
        h0b[o] = f2b(gelu_f((v - m_) * s + be));
    }
}

// ---------------------------------------------------------------- per-window mean of gelu(bn0(x)), f32 (exact)
__global__ __launch_bounds__(256) void hm_k(const float* __restrict__ xt,
    const float* __restrict__ g, const float* __restrict__ bt,
    const float* __restrict__ mu, const float* __restrict__ va,
    float* __restrict__ hm) {
    int blk = blockIdx.x;           // b*64 + win
    int b = blk >> 6, win = blk & 63;
    int c = threadIdx.x;
    int base = (win >> 3) * 128 + (win & 7) * 4;
    float s = g[c] * rsqrtf(va[c] + EPSV);
    float m_ = mu[c], be = bt[c];
    float acc = 0.f;
    #pragma unroll
    for (int ty = 0; ty < 4; ++ty)
        #pragma unroll
        for (int tx = 0; tx < 4; ++tx) {
            float v = xt[((size_t)(b * 1024 + base + ty * 32 + tx)) * 256 + c];
            acc += gelu_f((v - m_) * s + be);
        }
    hm[(size_t)blk * 256 + c] = acc * (1.f / 16.f);
}

// ---------------------------------------------------------------- MFMA GEMM, 128x128 tile, BK=32
// C[b][m][n] = sum_k A[m][k]*X[b][n][k]; output stored transposed [b][n][m]
// MODE 0: store bf16 (qkv)
// MODE 1: w = C + res + bias(p0); store f32(outf) + bf16(outb)   (merge)
// MODE 2: store bf16 gelu(bn(C))                                  (w1)
// MODE 3: store f32 bn(C) + res                                   (w2)
template <int MODE>
__global__ __launch_bounds__(256) void mgemm(
    const unsigned short* __restrict__ A, const unsigned short* __restrict__ X,
    unsigned short* __restrict__ outb, float* __restrict__ outf,
    const float* __restrict__ res,
    const float* __restrict__ p0, const float* __restrict__ p1,
    const float* __restrict__ p2, const float* __restrict__ p3,
    int M, int Kd) {
    __shared__ __align__(16) unsigned short As[4096];   // [128 m][32 k]
    __shared__ __align__(16) unsigned short Bs[4096];   // [128 n][32 k]
    const int t = threadIdx.x;
    const int wid = t >> 6, lane = t & 63;
    const int n0 = blockIdx.x * 128, m0 = blockIdx.y * 128, b = blockIdx.z;
    const unsigned short* Ab = A + (size_t)m0 * Kd;
    const unsigned short* Xb = X + ((size_t)b * 1024 + n0) * Kd;

    const int srow = lane >> 2;          // 0..15 within 16-row chunk
    const int skb  = (lane & 3) * 8;     // k-elem offset
    const int wr = wid >> 1, wc = wid & 1;
    const int lr = lane & 15;
    const int lk = (lane >> 4) * 8;

    f32x4 acc[4][4] = {};

    for (int k0 = 0; k0 < Kd; k0 += 32) {
        #pragma unroll
        for (int i = 0; i < 2; ++i) {
            int chunk = wid * 2 + i;                       // 0..7
            int row = chunk * 16 + srow;
            gload16(Ab + (size_t)row * Kd + k0 + skb, &As[chunk * 512]);
            gload16(Xb + (size_t)row * Kd + k0 + skb, &Bs[chunk * 512]);
        }
        __syncthreads();   // drains vmcnt before barrier
        bf16x8 af[4], bfv[4];
        #pragma unroll
        for (int mi = 0; mi < 4; ++mi)
            af[mi] = *(const bf16x8*)&As[(wr * 64 + mi * 16 + lr) * 32 + lk];
        #pragma unroll
        for (int ni = 0; ni < 4; ++ni)
            bfv[ni] = *(const bf16x8*)&Bs[(wc * 64 + ni * 16 + lr) * 32 + lk];
        #pragma unroll
        for (int mi = 0; mi < 4; ++mi)
            #pragma unroll
            for (int ni = 0; ni < 4; ++ni)
                acc[mi][ni] = __builtin_amdgcn_mfma_f32_16x16x32_bf16(
                    af[mi], bfv[ni], acc[mi][ni], 0, 0, 0);
        __syncthreads();
    }

    const int crow = (lane >> 4) * 4;   // m-offset base of the 4 acc regs
    #pragma unroll
    for (int ni = 0; ni < 4; ++ni) {
        const int n = n0 + wc * 64 + ni * 16 + lr;
        #pragma unroll
        for (int mi = 0; mi < 4; ++mi) {
            const int m = m0 + wr * 64 + mi * 16 + crow;
            f32x4 v = acc[mi][ni];
            size_t o = ((size_t)b * 1024 + n) * (size_t)M + m;
            if (MODE == 0) {
                *(ushort4*)(outb + o) = make_ushort4(f2b(v[0]), f2b(v[1]), f2b(v[2]), f2b(v[3]));
            } else if (MODE == 1) {
                float4 r = *(const float4*)(res + o);
                float4 bi = *(const float4*)(p0 + m);
                float w0 = v[0] + r.x + bi.x, w1 = v[1] + r.y + bi.y;
                float w2 = v[2] + r.z + bi.z, w3 = v[3] + r.w + bi.w;
                *(float4*)(outf + o) = make_float4(w0, w1, w2, w3);
                *(ushort4*)(outb + o) = make_ushort4(f2b(w0), f2b(w1), f2b(w2), f2b(w3));
            } else if (MODE == 2) {
                float4 gg = *(const float4*)(p0 + m);
                float4 be = *(const float4*)(p1 + m);
                float4 mm = *(const float4*)(p2 + m);
                float4 vv = *(const float4*)(p3 + m);
                float h0 = gelu_f((v[0] - mm.x) * (gg.x * rsqrtf(vv.x + EPSV)) + be.x);
                float h1 = gelu_f((v[1] - mm.y) * (gg.y * rsqrtf(vv.y + EPSV)) + be.y);
                float h2 = gelu_f((v[2] - mm.z) * (gg.z * rsqrtf(vv.z + EPSV)) + be.z);
                float h3 = gelu_f((v[3] - mm.w) * (gg.w * rsqrtf(vv.w + EPSV)) + be.w);
                *(ushort4*)(outb + o) = make_ushort4(f2b(h0), f2b(h1), f2b(h2), f2b(h3));
            } else {
                float4 gg = *(const float4*)(p0 + m);
                float4 be = *(const float4*)(p1 + m);
                float4 mm = *(const float4*)(p2 + m);
                float4 vv = *(const float4*)(p3 + m);
                float4 r = *(const float4*)(res + o);
                float y0 = (v[0] - mm.x) * (gg.x * rsqrtf(vv.x + EPSV)) + be.x + r.x;
                float y1 = (v[1] - mm.y) * (gg.y * rsqrtf(vv.y + EPSV)) + be.y + r.y;
                float y2 = (v[2] - mm.z) * (gg.z * rsqrtf(vv.z + EPSV)) + be.z + r.z;
                float y3 = (v[3] - mm.w) * (gg.w * rsqrtf(vv.w + EPSV)) + be.w + r.w;
                *(float4*)(outf + o) = make_float4(y0, y1, y2, y3);
            }
        }
    }
}

// ---------------------------------------------------------------- top-k from exact f32 descriptors
// qm[win] = W_q @ hm[win], km[win] = W_k @ hm[win] (linearity of mean)
__global__ __launch_bounds__(256) void topk2_k(const float* __restrict__ hm,
                                               const float* __restrict__ w_qkv,
                                               int* __restrict__ idx_out) {
    int bh = blockIdx.x; int b = bh >> 3, h = bh & 7;
    __shared__ float hmc[64][33];
    __shared__ float wqc[32][33];
    __shared__ float wkc[32][33];
    __shared__ float qm[64][33];
    __shared__ float km[64][33];
    __shared__ float wsc[64][65];
    int t = threadIdx.x;
    const float* hb = hm + (size_t)b * 64 * 256;
    const float* wq = w_qkv + (size_t)(h * 32) * 256;
    const float* wk = w_qkv + (size_t)(256 + h * 32) * 256;
    int win = t >> 2;            // this thread's output window
    int db  = (t & 3) * 8;       // 8 d's per thread
    float aq[8] = {0,0,0,0,0,0,0,0}, ak[8] = {0,0,0,0,0,0,0,0};
    for (int c0 = 0; c0 < 256; c0 += 32) {
        for (int e = t; e < 2048; e += 256) {
            int wn = e >> 5, cc = e & 31;
            hmc[wn][cc] = hb[wn * 256 + c0 + cc];
        }
        for (int e = t; e < 1024; e += 256) {
            int d = e >> 5, cc = e & 31;
            wqc[d][cc] = wq[d * 256 + c0 + cc];
            wkc[d][cc] = wk[d * 256 + c0 + cc];
        }
        __syncthreads();
        #pragma unroll
        for (int cc = 0; cc < 32; ++cc) {
            float hv = hmc[win][cc];
            #pragma unroll
            for (int j = 0; j < 8; ++j) {
                aq[j] += wqc[db + j][cc] * hv;
                ak[j] += wkc[db + j][cc] * hv;
            }
        }
        __syncthreads();
    }
    #pragma unroll
    for (int j = 0; j < 8; ++j) { qm[win][db + j] = aq[j]; km[win][db + j] = ak[j]; }
    __syncthreads();
    for (int e = t; e < 4096; e += 256) {
        int i = e >> 6, j = e & 63;
        float s = 0.f;
        #pragma unroll
        for (int d = 0; d < 32; ++d) s += qm[i][d] * km[j][d];
        wsc[i][j] = s;   // positive scale irrelevant for ranking
    }
    __syncthreads();
    if (t < 64) {
        float bv[4] = {-1e30f, -1e30f, -1e30f, -1e30f};
        int   bi[4] = {0, 0, 0, 0};
        for (int j = 0; j < 64; ++j) {
            float v = wsc[t][j];
            if (v > bv[3]) {
                int p = 3;
                while (p > 0 && v > bv[p - 1]) {
                    bv[p] = bv[p - 1]; bi[p] = bi[p - 1]; --p;
                }
                bv[p] = v; bi[p] = j;
            }
        }
        int* o = idx_out + (bh * 64 + t) * 4;
        o[0] = bi[0]; o[1] = bi[1]; o[2] = bi[2]; o[3] = bi[3];
    }
}

// ---------------------------------------------------------------- gathered window attention (NHWC bf16)
__global__ __launch_bounds__(256) void attn_k(const unsigned short* __restrict__ qkv,
                                              const int* __restrict__ idx,
                                              unsigned short* __restrict__ msg) {
    int blk = blockIdx.x;           // (b*8+h)*64 + win
    int win = blk & 63;
    int bh = blk >> 6;
    int b = bh >> 3, h = bh & 7;
    __shared__ float qs[16][32];
    __shared__ float ks[64][32];
    __shared__ float vs[64][32];
    __shared__ float sc[16][64];
    __shared__ int widx[4];
    int t = threadIdx.x;
    if (t < 4) widx[t] = idx[(bh * 64 + win) * 4 + t];
    __syncthreads();
    int qb = (win >> 3) * 128 + (win & 7) * 4;
    for (int e = t; e < 512; e += 256) {
        int tok = e >> 5, d = e & 31;
        int hw = qb + (tok >> 2) * 32 + (tok & 3);
        qs[tok][d] = b2f(qkv[((size_t)(b * 1024 + hw)) * 768 + h * 32 + d]);
    }
    for (int e = t; e < 2048; e += 256) {
        int key = e >> 5, d = e & 31;
        int wsel = widx[key >> 4];
        int tok = key & 15;
        int hw = (wsel >> 3) * 128 + (wsel & 7) * 4 + (tok >> 2) * 32 + (tok & 3);
        size_t base = ((size_t)(b * 1024 + hw)) * 768 + h * 32 + d;
        ks[key][d] = b2f(qkv[base + 256]);
        vs[key][d] = b2f(qkv[base + 512]);
    }
    __syncthreads();
    const float scale = 0.17677669529663688f;   // 1/sqrt(32)
    for (int e = t; e < 1024; e += 256) {
        int r = e >> 6, cidx = e & 63;
        float s = 0.f;
        #pragma unroll
        for (int d = 0; d < 32; ++d) s += qs[r][d] * ks[cidx][d];
        sc[r][cidx] = s * scale;
    }
    __syncthreads();
    {
        int r = t >> 4, c0 = (t & 15) << 2;
        float v0 = sc[r][c0], v1 = sc[r][c0 + 1], v2 = sc[r][c0 + 2], v3 = sc[r][c0 + 3];
        float mx = fmaxf(fmaxf(v0, v1), fmaxf(v2, v3));
        #pragma unroll
        for (int m = 1; m < 16; m <<= 1) mx = fmaxf(mx, __shfl_xor(mx, m));
        float e0 = expf(v0 - mx), e1 = expf(v1 - mx), e2 = expf(v2 - mx), e3 = expf(v3 - mx);
        float sm = e0 + e1 + e2 + e3;
        #pragma unroll
        for (int m = 1; m < 16; m <<= 1) sm += __shfl_xor(sm, m);
        float inv = 1.0f / sm;
        sc[r][c0] = e0 * inv; sc[r][c0 + 1] = e1 * inv;
        sc[r][c0 + 2] = e2 * inv; sc[r][c0 + 3] = e3 * inv;
    }
    __syncthreads();
    for (int e = t; e < 512; e += 256) {
        int tok = e >> 5, d = e & 31;
        float s = 0.f;
        #pragma unroll
        for (int kk = 0; kk < 64; ++kk) s += sc[tok][kk] * vs[kk][d];
        int hw = qb + (tok >> 2) * 32 + (tok & 3);
        msg[((size_t)(b * 1024 + hw)) * 256 + h * 32 + d] = f2b(s);
    }
}

// ---------------------------------------------------------------- depthwise 3x3 + bn2 + gelu (NHWC bf16)
__global__ __launch_bounds__(256) void dw_k(const unsigned short* __restrict__ h1,
    const float* __restrict__ wdw,
    const float* __restrict__ g, const float* __restrict__ bt,
    const float* __restrict__ mu, const float* __restrict__ va,
    unsigned short* __restrict__ h2) {
    int i = blockIdx.x * 256 + threadIdx.x;   // [b][hw][ch]
    int ch = i & 1023, hw = (i >> 10) & 1023, b = i >> 20;
    int yh = hw >> 5, xw = hw & 31;
    const unsigned short* base = h1 + (size_t)b * 1048576;
    const float* w9 = wdw + ch * 9;
    float acc = 0.f;
    #pragma unroll
    for (int dy = -1; dy <= 1; ++dy) {
        int yy = yh + dy;
        if (yy < 0 || yy > 31) continue;
        #pragma unroll
        for (int dx = -1; dx <= 1; ++dx) {
            int xx = xw + dx;
            if (xx < 0 || xx > 31) continue;
            acc += b2f(base[(size_t)(yy * 32 + xx) * 1024 + ch]) * w9[(dy + 1) * 3 + (dx + 1)];
        }
    }
    float s = g[ch] * rsqrtf(va[ch] + EPSV);
    h2[i] = f2b(gelu_f((acc - mu[ch]) * s + bt[ch]));
}

// ---------------------------------------------------------------- NHWC f32 -> NCHW f32 (final)
__global__ __launch_bounds__(256) void trout_k(const float* __restrict__ y,
                                               float* __restrict__ out) {
    __shared__ float tile[64][65];
    int hw0 = blockIdx.x * 64, c0 = blockIdx.y * 64, b = blockIdx.z;
    int t = threadIdx.x;
    #pragma unroll
    for (int r = 0; r < 16; ++r) {
        int hl = r * 4 + (t >> 6);
        tile[t & 63][hl] = y[((size_t)(b * 1024 + hw0 + hl)) * 256 + c0 + (t & 63)];
    }
    __syncthreads();
    #pragma unroll
    for (int r = 0; r < 16; ++r) {
        int cl = r * 4 + (t >> 6);
        out[((size_t)(b * 256 + c0 + cl)) * 1024 + hw0 + (t & 63)] = tile[cl][t & 63];
    }
}

// ---------------------------------------------------------------- launch
extern "C" void kernel_launch(void* const* d_in, const int* in_sizes, int n_in,
                              void* d_out, int out_size, void* d_ws, size_t ws_size,
                              hipStream_t stream) {
    const float* x      = (const float*)d_in[0];
    const float* bn0_g  = (const float*)d_in[1];
    const float* bn0_b  = (const float*)d_in[2];
    const float* bn0_m  = (const float*)d_in[3];
    const float* bn0_v  = (const float*)d_in[4];
    const float* w_qkv  = (const float*)d_in[5];
    const float* w_merge= (const float*)d_in[6];
    const float* b_merge= (const float*)d_in[7];
    const float* w1     = (const float*)d_in[8];
    const float* bn1_g  = (const float*)d_in[9];
    const float* bn1_b  = (const float*)d_in[10];
    const float* bn1_m  = (const float*)d_in[11];
    const float* bn1_v  = (const float*)d_in[12];
    const float* dw     = (const float*)d_in[13];
    const float* bn2_g  = (const float*)d_in[14];
    const float* bn2_b  = (const float*)d_in[15];
    const float* bn2_m  = (const float*)d_in[16];
    const float* bn2_v  = (const float*)d_in[17];
    const float* w2     = (const float*)d_in[18];
    const float* bn3_g  = (const float*)d_in[19];
    const float* bn3_b  = (const float*)d_in[20];
    const float* bn3_m  = (const float*)d_in[21];
    const float* bn3_v  = (const float*)d_in[22];
    float* out = (float*)d_out;

    char* w = (char*)d_ws;                                 // ~170.5 MB total
    unsigned short* h0b   = (unsigned short*)(w);                // [b][hw][256] bf16
    unsigned short* qkvb  = (unsigned short*)(w + 8388608);      // [b][hw][768] bf16
    unsigned short* msgb  = (unsigned short*)(w + 33554432);     // [b][hw][256] bf16
    unsigned short* xrb   = (unsigned short*)(w + 41943040);     // [b][hw][256] bf16
    unsigned short* h1b   = (unsigned short*)(w + 50331648);     // [b][hw][1024] bf16
    unsigned short* h2b   = (unsigned short*)(w + 83886080);     // [b][hw][1024] bf16
    float*  xt    = (float*)(w + 117440512);                     // [b][hw][256] f32 (raw x)
    float*  xrf   = (float*)(w + 134217728);                     // [b][hw][256] f32
    float*  yf    = (float*)(w + 150994944);                     // [b][hw][256] f32
    float*  hm    = (float*)(w + 167772160);                     // [b][64][256] f32
    unsigned short* wqkvb = (unsigned short*)(w + 168820736);
    unsigned short* wmrgb = (unsigned short*)(w + 169213952);
    unsigned short* w1b   = (unsigned short*)(w + 169345024);
    unsigned short* w2b   = (unsigned short*)(w + 169869312);
    int*    idx   = (int*)(w + 170393600);

    // weights -> bf16
    wcvt_k<<<192, 256, 0, stream>>>(w_qkv, wqkvb, 49152);
    wcvt_k<<<64,  256, 0, stream>>>(w_merge, wmrgb, 16384);
    wcvt_k<<<256, 256, 0, stream>>>(w1, w1b, 65536);
    wcvt_k<<<256, 256, 0, stream>>>(w2, w2b, 65536);

    // bn0+gelu + transpose to NHWC
    bn0tr_k<<<dim3(16, 4, 16), 256, 0, stream>>>(x, bn0_g, bn0_b, bn0_m, bn0_v, h0b, xt);
    // exact f32 window means
    hm_k<<<1024, 256, 0, stream>>>(xt, bn0_g, bn0_b, bn0_m, bn0_v, hm);
    // qkv = w_qkv @ h0  -> [b][hw][768] bf16
    mgemm<0><<<dim3(8, 6, 16), 256, 0, stream>>>(wqkvb, h0b, qkvb, nullptr,
        nullptr, nullptr, nullptr, nullptr, nullptr, 768, 256);
    // top-k (f32-exact descriptors)
    topk2_k<<<128, 256, 0, stream>>>(hm, w_qkv, idx);
    // attention
    attn_k<<<8192, 256, 0, stream>>>(qkvb, idx, msgb);
    // xr = x + w_merge@msg + bias  (f32 + bf16 copies)
    mgemm<1><<<dim3(8, 2, 16), 256, 0, stream>>>(wmrgb, msgb, xrb, xrf,
        xt, b_merge, nullptr, nullptr, nullptr, 256, 256);
    // h1 = gelu(bn1(w1@xr))
    mgemm<2><<<dim3(8, 8, 16), 256, 0, stream>>>(w1b, xrb, h1b, nullptr,
        nullptr, bn1_g, bn1_b, bn1_m, bn1_v, 1024, 256);
    // h2 = gelu(bn2(dw3x3(h1)))
    dw_k<<<65536, 256, 0, stream>>>(h1b, dw, bn2_g, bn2_b, bn2_m, bn2_v, h2b);
    // y = bn3(w2@h2) + xr  (f32 NHWC)
    mgemm<3><<<dim3(8, 2, 16), 256, 0, stream>>>(w2b, h2b, nullptr, yf,
        xrf, bn3_g, bn3_b, bn3_m, bn3_v, 256, 1024);
    // NHWC -> NCHW
    trout_k<<<dim3(16, 4, 16), 256, 0, stream>>>(yf, out);
}

// Round 6
// 404.955 us; speedup vs baseline: 1.7332x; 1.2236x over previous
//
#include <hip/hip_runtime.h>
#include <hip/hip_bf16.h>

#define EPSV 1e-5f

typedef short bf16x8 __attribute__((ext_vector_type(8)));
typedef float f32x4 __attribute__((ext_vector_type(4)));

__device__ __forceinline__ float gelu_f(float x) {
    return 0.5f * x * (1.0f + erff(x * 0.70710678118654752f));
}
__device__ __forceinline__ float b2f(unsigned short u) {
    union { float f; unsigned i; } c; c.i = ((unsigned)u) << 16; return c.f;
}
__device__ __forceinline__ unsigned short f2b(float f) {
    __hip_bfloat16 h = __float2bfloat16(f);
    return *reinterpret_cast<unsigned short*>(&h);
}
__device__ __forceinline__ float lo16f(unsigned v) {
    union { float f; unsigned i; } c; c.i = v << 16; return c.f;
}
__device__ __forceinline__ float hi16f(unsigned v) {
    union { float f; unsigned i; } c; c.i = v & 0xffff0000u; return c.f;
}
// async global->LDS, 16B per lane; LDS dest = wave-uniform base + lane*16
__device__ __forceinline__ void gload16(const unsigned short* g, unsigned short* l) {
    __builtin_amdgcn_global_load_lds(
        (const __attribute__((address_space(1))) void*)g,
        (__attribute__((address_space(3))) void*)l, 16, 0, 0);
}

// ---------------------------------------------------------------- weight f32->bf16
__global__ __launch_bounds__(256) void wcvt_k(const float* __restrict__ w,
                                              unsigned short* __restrict__ o, int n4) {
    int i = blockIdx.x * 256 + threadIdx.x;
    if (i >= n4) return;
    float4 v = ((const float4*)w)[i];
    ushort4 u = make_ushort4(f2b(v.x), f2b(v.y), f2b(v.z), f2b(v.w));
    ((ushort4*)o)[i] = u;
}

// ---------------------------------------------------------------- dw weight transpose + bn2 fold
// wt[tap][ch] = dw[ch][tap]; scf[ch]=g/sqrt(v+eps); shf[ch]=bt-mu*scf
__global__ __launch_bounds__(256) void wprep_k(const float* __restrict__ wdw,
    const float* __restrict__ g, const float* __restrict__ bt,
    const float* __restrict__ mu, const float* __restrict__ va,
    float* __restrict__ wt, float* __restrict__ scf, float* __restrict__ shf) {
    int ch = blockIdx.x * 256 + threadIdx.x;   // 1024 total
    #pragma unroll
    for (int tap = 0; tap < 9; ++tap)
        wt[tap * 1024 + ch] = wdw[ch * 9 + tap];
    float s = g[ch] * rsqrtf(va[ch] + EPSV);
    scf[ch] = s;
    shf[ch] = bt[ch] - mu[ch] * s;
}

// ---------------------------------------------------------------- bn0+gelu + NCHW->NHWC
__global__ __launch_bounds__(256) void bn0tr_k(const float* __restrict__ x,
    const float* __restrict__ g, const float* __restrict__ bt,
    const float* __restrict__ mu, const float* __restrict__ va,
    unsigned short* __restrict__ h0b, float* __restrict__ xt) {
    __shared__ float tile[64][65];
    int hw0 = blockIdx.x * 64, c0 = blockIdx.y * 64, b = blockIdx.z;
    int t = threadIdx.x;
    int cl = t >> 6, hl = t & 63;
    #pragma unroll
    for (int r = 0; r < 16; ++r)
        tile[r * 4 + cl][hl] = x[((size_t)(b * 256 + c0 + r * 4 + cl)) * 1024 + hw0 + hl];
    __syncthreads();
    int c = c0 + (t & 63);
    float s = g[c] * rsqrtf(va[c] + EPSV);
    float m_ = mu[c], be = bt[c];
    #pragma unroll
    for (int r = 0; r < 16; ++r) {
        int hl2 = r * 4 + (t >> 6);
        float v = tile[t & 63][hl2];
        size_t o = ((size_t)(b * 1024 + hw0 + hl2)) * 256 + c;
        xt[o] = v;
        h0b[o] = f2b(gelu_f((v - m_) * s + be));
    }
}

// ---------------------------------------------------------------- per-window mean of gelu(bn0(x)), f32 (exact)
__global__ __launch_bounds__(256) void hm_k(const float* __restrict__ xt,
    const float* __restrict__ g, const float* __restrict__ bt,
    const float* __restrict__ mu, const float* __restrict__ va,
    float* __restrict__ hm) {
    int blk = blockIdx.x;           // b*64 + win
    int b = blk >> 6, win = blk & 63;
    int c = threadIdx.x;
    int base = (win >> 3) * 128 + (win & 7) * 4;
    float s = g[c] * rsqrtf(va[c] + EPSV);
    float m_ = mu[c], be = bt[c];
    float acc = 0.f;
    #pragma unroll
    for (int ty = 0; ty < 4; ++ty)
        #pragma unroll
        for (int tx = 0; tx < 4; ++tx) {
            float v = xt[((size_t)(b * 1024 + base + ty * 32 + tx)) * 256 + c];
            acc += gelu_f((v - m_) * s + be);
        }
    hm[(size_t)blk * 256 + c] = acc * (1.f / 16.f);
}

// ---------------------------------------------------------------- MFMA GEMM, 128x128 tile, BK=32
// C[b][m][n] = sum_k A[m][k]*X[b][n][k]; output stored transposed [b][n][m]
template <int MODE>
__global__ __launch_bounds__(256) void mgemm(
    const unsigned short* __restrict__ A, const unsigned short* __restrict__ X,
    unsigned short* __restrict__ outb, float* __restrict__ outf,
    const float* __restrict__ res,
    const float* __restrict__ p0, const float* __restrict__ p1,
    const float* __restrict__ p2, const float* __restrict__ p3,
    int M, int Kd) {
    __shared__ __align__(16) unsigned short As[4096];   // [128 m][32 k]
    __shared__ __align__(16) unsigned short Bs[4096];   // [128 n][32 k]
    const int t = threadIdx.x;
    const int wid = t >> 6, lane = t & 63;
    const int n0 = blockIdx.x * 128, m0 = blockIdx.y * 128, b = blockIdx.z;
    const unsigned short* Ab = A + (size_t)m0 * Kd;
    const unsigned short* Xb = X + ((size_t)b * 1024 + n0) * Kd;

    const int srow = lane >> 2;
    const int skb  = (lane & 3) * 8;
    const int wr = wid >> 1, wc = wid & 1;
    const int lr = lane & 15;
    const int lk = (lane >> 4) * 8;

    f32x4 acc[4][4] = {};

    for (int k0 = 0; k0 < Kd; k0 += 32) {
        #pragma unroll
        for (int i = 0; i < 2; ++i) {
            int chunk = wid * 2 + i;
            int row = chunk * 16 + srow;
            gload16(Ab + (size_t)row * Kd + k0 + skb, &As[chunk * 512]);
            gload16(Xb + (size_t)row * Kd + k0 + skb, &Bs[chunk * 512]);
        }
        __syncthreads();
        bf16x8 af[4], bfv[4];
        #pragma unroll
        for (int mi = 0; mi < 4; ++mi)
            af[mi] = *(const bf16x8*)&As[(wr * 64 + mi * 16 + lr) * 32 + lk];
        #pragma unroll
        for (int ni = 0; ni < 4; ++ni)
            bfv[ni] = *(const bf16x8*)&Bs[(wc * 64 + ni * 16 + lr) * 32 + lk];
        #pragma unroll
        for (int mi = 0; mi < 4; ++mi)
            #pragma unroll
            for (int ni = 0; ni < 4; ++ni)
                acc[mi][ni] = __builtin_amdgcn_mfma_f32_16x16x32_bf16(
                    af[mi], bfv[ni], acc[mi][ni], 0, 0, 0);
        __syncthreads();
    }

    const int crow = (lane >> 4) * 4;
    #pragma unroll
    for (int ni = 0; ni < 4; ++ni) {
        const int n = n0 + wc * 64 + ni * 16 + lr;
        #pragma unroll
        for (int mi = 0; mi < 4; ++mi) {
            const int m = m0 + wr * 64 + mi * 16 + crow;
            f32x4 v = acc[mi][ni];
            size_t o = ((size_t)b * 1024 + n) * (size_t)M + m;
            if (MODE == 0) {
                *(ushort4*)(outb + o) = make_ushort4(f2b(v[0]), f2b(v[1]), f2b(v[2]), f2b(v[3]));
            } else if (MODE == 1) {
                float4 r = *(const float4*)(res + o);
                float4 bi = *(const float4*)(p0 + m);
                float w0 = v[0] + r.x + bi.x, w1 = v[1] + r.y + bi.y;
                float w2 = v[2] + r.z + bi.z, w3 = v[3] + r.w + bi.w;
                *(float4*)(outf + o) = make_float4(w0, w1, w2, w3);
                *(ushort4*)(outb + o) = make_ushort4(f2b(w0), f2b(w1), f2b(w2), f2b(w3));
            } else if (MODE == 2) {
                float4 gg = *(const float4*)(p0 + m);
                float4 be = *(const float4*)(p1 + m);
                float4 mm = *(const float4*)(p2 + m);
                float4 vv = *(const float4*)(p3 + m);
                float h0 = gelu_f((v[0] - mm.x) * (gg.x * rsqrtf(vv.x + EPSV)) + be.x);
                float h1 = gelu_f((v[1] - mm.y) * (gg.y * rsqrtf(vv.y + EPSV)) + be.y);
                float h2 = gelu_f((v[2] - mm.z) * (gg.z * rsqrtf(vv.z + EPSV)) + be.z);
                float h3 = gelu_f((v[3] - mm.w) * (gg.w * rsqrtf(vv.w + EPSV)) + be.w);
                *(ushort4*)(outb + o) = make_ushort4(f2b(h0), f2b(h1), f2b(h2), f2b(h3));
            } else {
                float4 gg = *(const float4*)(p0 + m);
                float4 be = *(const float4*)(p1 + m);
                float4 mm = *(const float4*)(p2 + m);
                float4 vv = *(const float4*)(p3 + m);
                float4 r = *(const float4*)(res + o);
                float y0 = (v[0] - mm.x) * (gg.x * rsqrtf(vv.x + EPSV)) + be.x + r.x;
                float y1 = (v[1] - mm.y) * (gg.y * rsqrtf(vv.y + EPSV)) + be.y + r.y;
                float y2 = (v[2] - mm.z) * (gg.z * rsqrtf(vv.z + EPSV)) + be.z + r.z;
                float y3 = (v[3] - mm.w) * (gg.w * rsqrtf(vv.w + EPSV)) + be.w + r.w;
                *(float4*)(outf + o) = make_float4(y0, y1, y2, y3);
            }
        }
    }
}

// ---------------------------------------------------------------- top-k from exact f32 descriptors
__global__ __launch_bounds__(256) void topk2_k(const float* __restrict__ hm,
                                               const float* __restrict__ w_qkv,
                                               int* __restrict__ idx_out) {
    int bh = blockIdx.x; int b = bh >> 3, h = bh & 7;
    __shared__ float hmc[64][33];
    __shared__ float wqc[32][33];
    __shared__ float wkc[32][33];
    __shared__ float qm[64][33];
    __shared__ float km[64][33];
    __shared__ float wsc[64][65];
    int t = threadIdx.x;
    const float* hb = hm + (size_t)b * 64 * 256;
    const float* wq = w_qkv + (size_t)(h * 32) * 256;
    const float* wk = w_qkv + (size_t)(256 + h * 32) * 256;
    int win = t >> 2;
    int db  = (t & 3) * 8;
    float aq[8] = {0,0,0,0,0,0,0,0}, ak[8] = {0,0,0,0,0,0,0,0};
    for (int c0 = 0; c0 < 256; c0 += 32) {
        for (int e = t; e < 2048; e += 256) {
            int wn = e >> 5, cc = e & 31;
            hmc[wn][cc] = hb[wn * 256 + c0 + cc];
        }
        for (int e = t; e < 1024; e += 256) {
            int d = e >> 5, cc = e & 31;
            wqc[d][cc] = wq[d * 256 + c0 + cc];
            wkc[d][cc] = wk[d * 256 + c0 + cc];
        }
        __syncthreads();
        #pragma unroll
        for (int cc = 0; cc < 32; ++cc) {
            float hv = hmc[win][cc];
            #pragma unroll
            for (int j = 0; j < 8; ++j) {
                aq[j] += wqc[db + j][cc] * hv;
                ak[j] += wkc[db + j][cc] * hv;
            }
        }
        __syncthreads();
    }
    #pragma unroll
    for (int j = 0; j < 8; ++j) { qm[win][db + j] = aq[j]; km[win][db + j] = ak[j]; }
    __syncthreads();
    for (int e = t; e < 4096; e += 256) {
        int i = e >> 6, j = e & 63;
        float s = 0.f;
        #pragma unroll
        for (int d = 0; d < 32; ++d) s += qm[i][d] * km[j][d];
        wsc[i][j] = s;
    }
    __syncthreads();
    if (t < 64) {
        float bv[4] = {-1e30f, -1e30f, -1e30f, -1e30f};
        int   bi[4] = {0, 0, 0, 0};
        for (int j = 0; j < 64; ++j) {
            float v = wsc[t][j];
            if (v > bv[3]) {
                int p = 3;
                while (p > 0 && v > bv[p - 1]) {
                    bv[p] = bv[p - 1]; bi[p] = bi[p - 1]; --p;
                }
                bv[p] = v; bi[p] = j;
            }
        }
        int* o = idx_out + (bh * 64 + t) * 4;
        o[0] = bi[0]; o[1] = bi[1]; o[2] = bi[2]; o[3] = bi[3];
    }
}

// ---------------------------------------------------------------- gathered window attention (NHWC bf16)
__global__ __launch_bounds__(256) void attn_k(const unsigned short* __restrict__ qkv,
                                              const int* __restrict__ idx,
                                              unsigned short* __restrict__ msg) {
    int blk = blockIdx.x;
    int win = blk & 63;
    int bh = blk >> 6;
    int b = bh >> 3, h = bh & 7;
    __shared__ float qs[16][32];
    __shared__ float ks[64][32];
    __shared__ float vs[64][32];
    __shared__ float sc[16][64];
    __shared__ int widx[4];
    int t = threadIdx.x;
    if (t < 4) widx[t] = idx[(bh * 64 + win) * 4 + t];
    __syncthreads();
    int qb = (win >> 3) * 128 + (win & 7) * 4;
    for (int e = t; e < 512; e += 256) {
        int tok = e >> 5, d = e & 31;
        int hw = qb + (tok >> 2) * 32 + (tok & 3);
        qs[tok][d] = b2f(qkv[((size_t)(b * 1024 + hw)) * 768 + h * 32 + d]);
    }
    for (int e = t; e < 2048; e += 256) {
        int key = e >> 5, d = e & 31;
        int wsel = widx[key >> 4];
        int tok = key & 15;
        int hw = (wsel >> 3) * 128 + (wsel & 7) * 4 + (tok >> 2) * 32 + (tok & 3);
        size_t base = ((size_t)(b * 1024 + hw)) * 768 + h * 32 + d;
        ks[key][d] = b2f(qkv[base + 256]);
        vs[key][d] = b2f(qkv[base + 512]);
    }
    __syncthreads();
    const float scale = 0.17677669529663688f;
    for (int e = t; e < 1024; e += 256) {
        int r = e >> 6, cidx = e & 63;
        float s = 0.f;
        #pragma unroll
        for (int d = 0; d < 32; ++d) s += qs[r][d] * ks[cidx][d];
        sc[r][cidx] = s * scale;
    }
    __syncthreads();
    {
        int r = t >> 4, c0 = (t & 15) << 2;
        float v0 = sc[r][c0], v1 = sc[r][c0 + 1], v2 = sc[r][c0 + 2], v3 = sc[r][c0 + 3];
        float mx = fmaxf(fmaxf(v0, v1), fmaxf(v2, v3));
        #pragma unroll
        for (int m = 1; m < 16; m <<= 1) mx = fmaxf(mx, __shfl_xor(mx, m));
        float e0 = expf(v0 - mx), e1 = expf(v1 - mx), e2 = expf(v2 - mx), e3 = expf(v3 - mx);
        float sm = e0 + e1 + e2 + e3;
        #pragma unroll
        for (int m = 1; m < 16; m <<= 1) sm += __shfl_xor(sm, m);
        float inv = 1.0f / sm;
        sc[r][c0] = e0 * inv; sc[r][c0 + 1] = e1 * inv;
        sc[r][c0 + 2] = e2 * inv; sc[r][c0 + 3] = e3 * inv;
    }
    __syncthreads();
    for (int e = t; e < 512; e += 256) {
        int tok = e >> 5, d = e & 31;
        float s = 0.f;
        #pragma unroll
        for (int kk = 0; kk < 64; ++kk) s += sc[tok][kk] * vs[kk][d];
        int hw = qb + (tok >> 2) * 32 + (tok & 3);
        msg[((size_t)(b * 1024 + hw)) * 256 + h * 32 + d] = f2b(s);
    }
}

// ---------------------------------------------------------------- K5: depthwise 3x3 + bn2 + gelu, vectorized
// thread = 8 channels x 4 pixels; weights register-cached from transposed wt[tap][ch]
__global__ __launch_bounds__(256) void dw_k(const unsigned short* __restrict__ h1,
    const float* __restrict__ wt, const float* __restrict__ scf,
    const float* __restrict__ shf, unsigned short* __restrict__ h2) {
    int t = threadIdx.x;
    int c8 = t & 127;             // channel octet 0..127
    int pl = t >> 7;              // 0/1
    int blk = blockIdx.x;         // 2048 total: b(16) * y(32) * xg(4)
    int b = blk >> 7;
    int rem = blk & 127;
    int y = rem >> 2;
    int x0 = (rem & 3) * 8;
    int ch0 = c8 * 8;

    // register-cache folded weights for these 8 channels (coalesced float4 loads)
    float w[9][8];
    #pragma unroll
    for (int tap = 0; tap < 9; ++tap) {
        float4 a = *(const float4*)(wt + tap * 1024 + ch0);
        float4 bq = *(const float4*)(wt + tap * 1024 + ch0 + 4);
        w[tap][0] = a.x; w[tap][1] = a.y; w[tap][2] = a.z; w[tap][3] = a.w;
        w[tap][4] = bq.x; w[tap][5] = bq.y; w[tap][6] = bq.z; w[tap][7] = bq.w;
    }
    float sc[8], sh[8];
    {
        float4 a = *(const float4*)(scf + ch0);
        float4 bq = *(const float4*)(scf + ch0 + 4);
        sc[0]=a.x; sc[1]=a.y; sc[2]=a.z; sc[3]=a.w; sc[4]=bq.x; sc[5]=bq.y; sc[6]=bq.z; sc[7]=bq.w;
        float4 c = *(const float4*)(shf + ch0);
        float4 dq = *(const float4*)(shf + ch0 + 4);
        sh[0]=c.x; sh[1]=c.y; sh[2]=c.z; sh[3]=c.w; sh[4]=dq.x; sh[5]=dq.y; sh[6]=dq.z; sh[7]=dq.w;
    }

    const unsigned short* base = h1 + (size_t)b * 1048576;
    unsigned short* ob = h2 + (size_t)b * 1048576;

    #pragma unroll
    for (int j = 0; j < 4; ++j) {
        int x = x0 + pl + 2 * j;
        float acc[8] = {0.f,0.f,0.f,0.f,0.f,0.f,0.f,0.f};
        #pragma unroll
        for (int dy = -1; dy <= 1; ++dy) {
            int yy = y + dy;
            if (yy < 0 || yy > 31) continue;
            #pragma unroll
            for (int dx = -1; dx <= 1; ++dx) {
                int xx = x + dx;
                if (xx < 0 || xx > 31) continue;
                uint4 u = *(const uint4*)(base + (size_t)(yy * 32 + xx) * 1024 + ch0);
                int tap = (dy + 1) * 3 + (dx + 1);
                acc[0] += lo16f(u.x) * w[tap][0];
                acc[1] += hi16f(u.x) * w[tap][1];
                acc[2] += lo16f(u.y) * w[tap][2];
                acc[3] += hi16f(u.y) * w[tap][3];
                acc[4] += lo16f(u.z) * w[tap][4];
                acc[5] += hi16f(u.z) * w[tap][5];
                acc[6] += lo16f(u.w) * w[tap][6];
                acc[7] += hi16f(u.w) * w[tap][7];
            }
        }
        unsigned short r[8];
        #pragma unroll
        for (int c = 0; c < 8; ++c)
            r[c] = f2b(gelu_f(acc[c] * sc[c] + sh[c]));
        uint4 o;
        o.x = (unsigned)r[0] | ((unsigned)r[1] << 16);
        o.y = (unsigned)r[2] | ((unsigned)r[3] << 16);
        o.z = (unsigned)r[4] | ((unsigned)r[5] << 16);
        o.w = (unsigned)r[6] | ((unsigned)r[7] << 16);
        *(uint4*)(ob + (size_t)(y * 32 + x) * 1024 + ch0) = o;
    }
}

// ---------------------------------------------------------------- NHWC f32 -> NCHW f32 (final)
__global__ __launch_bounds__(256) void trout_k(const float* __restrict__ y,
                                               float* __restrict__ out) {
    __shared__ float tile[64][65];
    int hw0 = blockIdx.x * 64, c0 = blockIdx.y * 64, b = blockIdx.z;
    int t = threadIdx.x;
    #pragma unroll
    for (int r = 0; r < 16; ++r) {
        int hl = r * 4 + (t >> 6);
        tile[t & 63][hl] = y[((size_t)(b * 1024 + hw0 + hl)) * 256 + c0 + (t & 63)];
    }
    __syncthreads();
    #pragma unroll
    for (int r = 0; r < 16; ++r) {
        int cl = r * 4 + (t >> 6);
        out[((size_t)(b * 256 + c0 + cl)) * 1024 + hw0 + (t & 63)] = tile[cl][t & 63];
    }
}

// ---------------------------------------------------------------- launch
extern "C" void kernel_launch(void* const* d_in, const int* in_sizes, int n_in,
                              void* d_out, int out_size, void* d_ws, size_t ws_size,
                              hipStream_t stream) {
    const float* x      = (const float*)d_in[0];
    const float* bn0_g  = (const float*)d_in[1];
    const float* bn0_b  = (const float*)d_in[2];
    const float* bn0_m  = (const float*)d_in[3];
    const float* bn0_v  = (const float*)d_in[4];
    const float* w_qkv  = (const float*)d_in[5];
    const float* w_merge= (const float*)d_in[6];
    const float* b_merge= (const float*)d_in[7];
    const float* w1     = (const float*)d_in[8];
    const float* bn1_g  = (const float*)d_in[9];
    const float* bn1_b  = (const float*)d_in[10];
    const float* bn1_m  = (const float*)d_in[11];
    const float* bn1_v  = (const float*)d_in[12];
    const float* dw     = (const float*)d_in[13];
    const float* bn2_g  = (const float*)d_in[14];
    const float* bn2_b  = (const float*)d_in[15];
    const float* bn2_m  = (const float*)d_in[16];
    const float* bn2_v  = (const float*)d_in[17];
    const float* w2     = (const float*)d_in[18];
    const float* bn3_g  = (const float*)d_in[19];
    const float* bn3_b  = (const float*)d_in[20];
    const float* bn3_m  = (const float*)d_in[21];
    const float* bn3_v  = (const float*)d_in[22];
    float* out = (float*)d_out;

    char* w = (char*)d_ws;
    unsigned short* h0b   = (unsigned short*)(w);                // [b][hw][256] bf16
    unsigned short* qkvb  = (unsigned short*)(w + 8388608);      // [b][hw][768] bf16
    unsigned short* msgb  = (unsigned short*)(w + 33554432);     // [b][hw][256] bf16
    unsigned short* xrb   = (unsigned short*)(w + 41943040);     // [b][hw][256] bf16
    unsigned short* h1b   = (unsigned short*)(w + 50331648);     // [b][hw][1024] bf16
    unsigned short* h2b   = (unsigned short*)(w + 83886080);     // [b][hw][1024] bf16
    float*  xt    = (float*)(w + 117440512);                     // [b][hw][256] f32 (raw x)
    float*  xrf   = (float*)(w + 134217728);                     // [b][hw][256] f32
    float*  yf    = (float*)(w + 150994944);                     // [b][hw][256] f32
    float*  hm    = (float*)(w + 167772160);                     // [b][64][256] f32
    unsigned short* wqkvb = (unsigned short*)(w + 168820736);
    unsigned short* wmrgb = (unsigned short*)(w + 169213952);
    unsigned short* w1b   = (unsigned short*)(w + 169345024);
    unsigned short* w2b   = (unsigned short*)(w + 169869312);
    int*    idx   = (int*)(w + 170393600);                       // 131072 B
    float*  wtbuf = (float*)(w + 170524672);                     // 9*1024 f32
    float*  scbuf = (float*)(w + 170561536);                     // 1024 f32
    float*  shbuf = (float*)(w + 170565632);                     // 1024 f32

    // weights -> bf16 + dw prep
    wcvt_k<<<192, 256, 0, stream>>>(w_qkv, wqkvb, 49152);
    wcvt_k<<<64,  256, 0, stream>>>(w_merge, wmrgb, 16384);
    wcvt_k<<<256, 256, 0, stream>>>(w1, w1b, 65536);
    wcvt_k<<<256, 256, 0, stream>>>(w2, w2b, 65536);
    wprep_k<<<4, 256, 0, stream>>>(dw, bn2_g, bn2_b, bn2_m, bn2_v, wtbuf, scbuf, shbuf);

    // bn0+gelu + transpose to NHWC
    bn0tr_k<<<dim3(16, 4, 16), 256, 0, stream>>>(x, bn0_g, bn0_b, bn0_m, bn0_v, h0b, xt);
    // exact f32 window means
    hm_k<<<1024, 256, 0, stream>>>(xt, bn0_g, bn0_b, bn0_m, bn0_v, hm);
    // qkv = w_qkv @ h0
    mgemm<0><<<dim3(8, 6, 16), 256, 0, stream>>>(wqkvb, h0b, qkvb, nullptr,
        nullptr, nullptr, nullptr, nullptr, nullptr, 768, 256);
    // top-k (f32-exact descriptors)
    topk2_k<<<128, 256, 0, stream>>>(hm, w_qkv, idx);
    // attention
    attn_k<<<8192, 256, 0, stream>>>(qkvb, idx, msgb);
    // xr = x + w_merge@msg + bias
    mgemm<1><<<dim3(8, 2, 16), 256, 0, stream>>>(wmrgb, msgb, xrb, xrf,
        xt, b_merge, nullptr, nullptr, nullptr, 256, 256);
    // h1 = gelu(bn1(w1@xr))
    mgemm<2><<<dim3(8, 8, 16), 256, 0, stream>>>(w1b, xrb, h1b, nullptr,
        nullptr, bn1_g, bn1_b, bn1_m, bn1_v, 1024, 256);
    // h2 = gelu(bn2(dw3x3(h1)))  — vectorized
    dw_k<<<2048, 256, 0, stream>>>(h1b, wtbuf, scbuf, shbuf, h2b);
    // y = bn3(w2@h2) + xr  (f32 NHWC)
    mgemm<3><<<dim3(8, 2, 16), 256, 0, stream>>>(w2b, h2b, nullptr, yf,
        xrf, bn3_g, bn3_b, bn3_m, bn3_v, 256, 1024);
    // NHWC -> NCHW
    trout_k<<<dim3(16, 4, 16), 256, 0, stream>>>(yf, out);
}